// Round 2
// baseline (15.354 us; speedup 1.0000x reference)
//
#include <hip/hip_runtime.h>
#include <float.h>

typedef float f32x4 __attribute__((ext_vector_type(4)));
typedef float f32x2 __attribute__((ext_vector_type(2)));

#define T_DIM 256
#define C_DIM 1024
#define B_DIM 16
#define G_CH  4                 // channels per wave
#define ROWB  1024              // bytes per level row (256 floats)
#define REGB  (5 * ROWB)        // region: levels 1..5
#define WAVEB (2 * REGB)        // double-buffered regions per wave

// Compiler-only ordering fence (wavefront scope emits no waitcnt; per-wave DS
// ops execute in order in HW — validated empirically in R1, absmax 0).
__device__ __forceinline__ void wave_fence() {
    __builtin_amdgcn_fence(__ATOMIC_ACQ_REL, "wavefront");
    __builtin_amdgcn_wave_barrier();
}

__device__ __forceinline__ f32x4 vmax4(f32x4 a, f32x4 b) {
    f32x4 r;
    r.x = fmaxf(a.x, b.x); r.y = fmaxf(a.y, b.y);
    r.z = fmaxf(a.z, b.z); r.w = fmaxf(a.w, b.w);
    return r;
}

// byte offset of float position p within a level row, XOR-swizzled at 16B
// granularity: spreads positions 32 apart (lanes 8 apart) across banks.
__device__ __forceinline__ int swz(int p) {
    return (p << 2) ^ (((p >> 5) & 7) << 4);
}
// same swizzle for a 16B block index (lane-granular write/neighbor addresses)
__device__ __forceinline__ int swz16(int blk) {
    return (blk << 4) ^ (((blk >> 3) & 7) << 4);
}

__global__ __launch_bounds__(256) void pool_kernel(
    const float* __restrict__ feat,
    const float* __restrict__ reg,
    float* __restrict__ out)
{
    __shared__ __align__(16) char lds[4 * WAVEB];   // 40960 B -> 4 blocks/CU
    const int tid  = threadIdx.x;
    const int wv   = tid >> 6;
    const int lane = tid & 63;
    const int i0   = lane << 2;                 // first t of this thread

    const int b    = blockIdx.x >> 6;           // grid = 16 * 64
    const int cblk = blockIdx.x & 63;
    const int c0   = (cblk << 4) + wv * G_CH;   // 16 channels per block

    const int wavebase = wv * WAVEB;
    // precomputed addressing (amortized over G_CH channels)
    const int wbyte  = wavebase + swz16(lane);        // own write addr
    const int r1byte = wavebase + swz16(lane + 1);    // neighbor reads
    const int r2byte = wavebase + swz16(lane + 2);
    const int r4byte = wavebase + swz16(lane + 4);
    const int idx1   = (lane + 1) << 2;               // bpermute index

    // Per-element query offsets (depend only on (b,t); reused per channel)
    int qLa[4], qLb[4], qRa[4], qRb[4];
    bool zL[4], zR[4];
    {
        const float* rp = reg + ((size_t)b * T_DIM + i0) * 2;
        f32x4 ra = *(const f32x4*)rp;
        f32x4 rb = *(const f32x4*)(rp + 4);
        float r0v[4] = {ra.x, ra.z, rb.x, rb.z};   // reg[t][0]
        float r1v[4] = {ra.y, ra.w, rb.y, rb.w};   // reg[t][1]
        #pragma unroll
        for (int j = 0; j < 4; ++j) {
            int t = i0 + j;
            // left window [l, t+1), len 1..33
            int rl = (int)rintf(r0v[j]); rl = rl < 0 ? 0 : rl;
            int l = t - rl; l = l < 0 ? 0 : l;
            int lenL = t + 1 - l;
            int kL = 31 - __clz(lenL);
            int i2L = t + 1 - (1 << kL);
            // right window [t, re), len 1..32
            int rr = (int)rintf(r1v[j]); rr = rr < 1 ? 1 : rr;
            int re = t + rr; re = re > T_DIM ? T_DIM : re;
            int lenR = re - t;
            int kR = 31 - __clz(lenR);
            int i2R = re - (1 << kR);
            int rowL = (kL >= 1 ? kL - 1 : 0) * ROWB;   // level k at row k-1
            int rowR = (kR >= 1 ? kR - 1 : 0) * ROWB;
            qLa[j] = wavebase + rowL + swz(l);
            qLb[j] = wavebase + rowL + swz(i2L);
            qRa[j] = wavebase + rowR + swz(t);
            qRb[j] = wavebase + rowR + swz(i2R);
            zL[j] = (kL == 0);
            zR[j] = (kR == 0);
        }
    }

    // issue all channels' feat loads up front
    const size_t fbase = ((size_t)b * C_DIM + c0) * T_DIM + i0;
    f32x4 fv[G_CH];
    #pragma unroll
    for (int g = 0; g < G_CH; ++g)
        fv[g] = *(const f32x4*)(feat + fbase + (size_t)g * T_DIM);

    #pragma unroll
    for (int g = 0; g < G_CH; ++g) {
        const int R = (g & 1) * REGB;   // alternate table regions
        f32x4 f = fv[g];

        // level 1 (len 2): needs x[t+4] first elem from lane+1 via bpermute
        float x4 = __int_as_float(
            __builtin_amdgcn_ds_bpermute(idx1, __float_as_int(f.x)));
        f32x4 v1;
        v1.x = fmaxf(f.x, f.y); v1.y = fmaxf(f.y, f.z);
        v1.z = fmaxf(f.z, f.w); v1.w = fmaxf(f.w, x4);
        *(f32x4*)(lds + wbyte + (R + 0 * ROWB)) = v1;
        wave_fence();
        // level 2 (len 4): v2[p]=max(v1[p],v1[p+2]); needs v1[0:1] of lane+1
        f32x2 n1 = *(const f32x2*)(lds + r1byte + (R + 0 * ROWB));
        f32x4 v2;
        v2.x = fmaxf(v1.x, v1.z); v2.y = fmaxf(v1.y, v1.w);
        v2.z = fmaxf(v1.z, n1.x); v2.w = fmaxf(v1.w, n1.y);
        *(f32x4*)(lds + wbyte + (R + 1 * ROWB)) = v2;
        wave_fence();
        // level 3 (len 8): +4 = lane+1's v2
        f32x4 n2 = *(const f32x4*)(lds + r1byte + (R + 1 * ROWB));
        f32x4 v3 = vmax4(v2, n2);
        *(f32x4*)(lds + wbyte + (R + 2 * ROWB)) = v3;
        wave_fence();
        // level 4 (len 16): +8 = lane+2's v3
        f32x4 n3 = *(const f32x4*)(lds + r2byte + (R + 2 * ROWB));
        f32x4 v4 = vmax4(v3, n3);
        *(f32x4*)(lds + wbyte + (R + 3 * ROWB)) = v4;
        wave_fence();
        // level 5 (len 32): +16 = lane+4's v4
        f32x4 n4 = *(const f32x4*)(lds + r4byte + (R + 3 * ROWB));
        f32x4 v5 = vmax4(v4, n4);
        *(f32x4*)(lds + wbyte + (R + 4 * ROWB)) = v5;
        wave_fence();

        // queries: 12 scattered b32 reads (k==0 served from registers)
        f32x4 res;
        #pragma unroll
        for (int j = 0; j < 4; ++j) {
            float la = *(const float*)(lds + qLa[j] + R);
            float lb = *(const float*)(lds + qLb[j] + R);
            float ra = *(const float*)(lds + qRa[j] + R);
            float rb = *(const float*)(lds + qRb[j] + R);
            float fj = (j == 0) ? f.x : (j == 1) ? f.y : (j == 2) ? f.z : f.w;
            float left  = zL[j] ? fj : fmaxf(la, lb);
            float right = zR[j] ? fj : fmaxf(ra, rb);
            float v = left + right;
            if (j == 0) res.x = v;
            else if (j == 1) res.y = v;
            else if (j == 2) res.z = v;
            else res.w = v;
        }
        *(f32x4*)(out + fbase + (size_t)g * T_DIM) = res;
        // no tail fence: next channel uses the other region; the region reused
        // two channels later is protected by in-order per-wave DS execution
        wave_fence();
    }
}

extern "C" void kernel_launch(void* const* d_in, const int* in_sizes, int n_in,
                              void* d_out, int out_size, void* d_ws, size_t ws_size,
                              hipStream_t stream) {
    const float* feat = (const float*)d_in[0];
    const float* reg  = (const float*)d_in[1];
    float* out = (float*)d_out;
    // grid: B(16) * C/(4 waves * G_CH) = 16 * 64 = 1024 blocks, 4/CU
    pool_kernel<<<dim3(B_DIM * (C_DIM / (4 * G_CH))), 256, 0, stream>>>(feat, reg, out);
}